// Round 1
// baseline (225.488 us; speedup 1.0000x reference)
//
#include <hip/hip_runtime.h>

#define B_  2048
#define I_  256
#define H_  512
#define D_  768
#define K_  32

// ---------------- kernel 1: combT[d][b] = concat(x,h_prev)[b][d] ----------------
__global__ __launch_bounds__(256) void build_combT(
    const float* __restrict__ x, const float* __restrict__ hp,
    float* __restrict__ combT) {
  __shared__ float tile[32][33];
  int b0 = blockIdx.x * 32;
  int d0 = blockIdx.y * 32;
  int tx = threadIdx.x & 31;
  int ty = threadIdx.x >> 5;
#pragma unroll
  for (int i = 0; i < 4; ++i) {
    int row = ty + i * 8;           // b offset within tile
    int b = b0 + row;
    int d = d0 + tx;
    float v = (d < I_) ? x[b * I_ + d] : hp[b * H_ + (d - I_)];
    tile[row][tx] = v;
  }
  __syncthreads();
#pragma unroll
  for (int i = 0; i < 4; ++i) {
    int row = ty + i * 8;           // d offset within tile
    combT[(size_t)(d0 + row) * B_ + b0 + tx] = tile[tx][row];
  }
}

// ---------------- kernel 2: u[g][d][b] = per-feature MLP ----------------
// u = sum_k relu(comb*W1+b1)*W2 + b2
__global__ __launch_bounds__(256) void kan_phase1(
    const float* __restrict__ combT,
    const float* __restrict__ W1, const float* __restrict__ b1,
    const float* __restrict__ W2, const float* __restrict__ b2,
    float* __restrict__ u) {
  int gd = blockIdx.x;              // g*D + d
  int d  = gd % D_;
  int t  = threadIdx.x;
  const float* cT = combT + (size_t)d * B_;
  const int base = gd * K_;
  float bias = b2[gd];
  float c[8], acc[8];
#pragma unroll
  for (int j = 0; j < 8; ++j) { c[j] = cT[t + j * 256]; acc[j] = bias; }
#pragma unroll
  for (int k = 0; k < K_; ++k) {
    float w1 = W1[base + k];        // wave-uniform -> scalar loads
    float bb = b1[base + k];
    float w2 = W2[base + k];
#pragma unroll
    for (int j = 0; j < 8; ++j) {
      float h = fmaxf(fmaf(c[j], w1, bb), 0.0f);
      acc[j] = fmaf(h, w2, acc[j]);
    }
  }
  float* ug = u + (size_t)gd * B_;
#pragma unroll
  for (int j = 0; j < 8; ++j) ug[t + j * 256] = acc[j];
}

// ---------------- kernel 3: gates = u @ Wc + bc, then LSTM cell ----------------
#define BT 64
#define HT 64
#define DK 16
#define ND (D_ / DK)                 // 48

__global__ __launch_bounds__(256) void kan_phase2(
    const float* __restrict__ u, const float* __restrict__ Wc,
    const float* __restrict__ bc, const float* __restrict__ c_prev,
    float* __restrict__ out) {
  __shared__ float uS[4][DK][BT];
  __shared__ float wS[4][DK][HT];
  int b0 = blockIdx.x * BT;
  int h0 = blockIdx.y * HT;
  int t = threadIdx.x;
  int tb = t & 15, th = t >> 4;      // 16x16 thread grid, 4x4 outputs each

  float acc[4][16];
#pragma unroll
  for (int g = 0; g < 4; ++g)
#pragma unroll
    for (int i = 0; i < 16; ++i) acc[g][i] = 0.f;

  float4 ru[4], rw[4];

  auto load_tiles = [&](int dp) {
#pragma unroll
    for (int i = 0; i < 4; ++i) {
      int lin = t + i * 256;         // 0..1023
      int g = lin >> 8;
      int r = lin & 255;
      int dd = r >> 4;
      int q = r & 15;
      ru[i] = *(const float4*)&u[((size_t)g * D_ + dp + dd) * B_ + b0 + q * 4];
      rw[i] = *(const float4*)&Wc[((size_t)g * D_ + dp + dd) * H_ + h0 + q * 4];
    }
  };
  auto store_tiles = [&]() {
#pragma unroll
    for (int i = 0; i < 4; ++i) {
      int lin = t + i * 256;
      int g = lin >> 8;
      int r = lin & 255;
      int dd = r >> 4;
      int q = r & 15;
      *(float4*)&uS[g][dd][q * 4] = ru[i];
      *(float4*)&wS[g][dd][q * 4] = rw[i];
    }
  };

  load_tiles(0);
  for (int it = 0; it < ND; ++it) {
    __syncthreads();                 // previous compute done before overwrite
    store_tiles();
    __syncthreads();
    if (it + 1 < ND) load_tiles((it + 1) * DK);   // prefetch overlaps compute
#pragma unroll
    for (int dd = 0; dd < DK; ++dd) {
#pragma unroll
      for (int g = 0; g < 4; ++g) {
        float4 a4 = *(const float4*)&uS[g][dd][tb * 4];
        float4 w4 = *(const float4*)&wS[g][dd][th * 4];
        const float* ap = (const float*)&a4;
        const float* wp = (const float*)&w4;
#pragma unroll
        for (int i = 0; i < 4; ++i)
#pragma unroll
          for (int j = 0; j < 4; ++j)
            acc[g][i * 4 + j] = fmaf(ap[i], wp[j], acc[g][i * 4 + j]);
      }
    }
  }

  // ---- fused LSTM epilogue ----
#pragma unroll
  for (int i = 0; i < 4; ++i) {
    int b = b0 + tb * 4 + i;
    int h = h0 + th * 4;
    float4 cp4 = *(const float4*)&c_prev[(size_t)b * H_ + h];
    float hv[4], cv[4];
#pragma unroll
    for (int j = 0; j < 4; ++j) {
      float gf = acc[0][i * 4 + j] + bc[0 * H_ + h + j];
      float gi = acc[1][i * 4 + j] + bc[1 * H_ + h + j];
      float go = acc[2][i * 4 + j] + bc[2 * H_ + h + j];
      float gc = acc[3][i * 4 + j] + bc[3 * H_ + h + j];
      float ft  = 1.f / (1.f + __expf(-gf));
      float it_ = 1.f / (1.f + __expf(-gi));
      float ot  = 1.f / (1.f + __expf(-go));
      float ctl = tanhf(gc);
      float cold = ((const float*)&cp4)[j];
      float cn = ft * cold + it_ * ctl;
      cv[j] = cn;
      hv[j] = ot * tanhf(cn);
    }
    *(float4*)&out[(size_t)b * H_ + h] = *(float4*)hv;
    *(float4*)&out[(size_t)B_ * H_ + (size_t)b * H_ + h] = *(float4*)cv;
  }
}

extern "C" void kernel_launch(void* const* d_in, const int* in_sizes, int n_in,
                              void* d_out, int out_size, void* d_ws, size_t ws_size,
                              hipStream_t stream) {
  const float* x   = (const float*)d_in[0];
  const float* hp  = (const float*)d_in[1];
  const float* cp  = (const float*)d_in[2];
  const float* W1  = (const float*)d_in[3];
  const float* b1  = (const float*)d_in[4];
  const float* W2  = (const float*)d_in[5];
  const float* b2  = (const float*)d_in[6];
  const float* Wc  = (const float*)d_in[7];
  const float* bc  = (const float*)d_in[8];
  float* out = (float*)d_out;

  float* combT = (float*)d_ws;                        // D*B floats   (6.3 MB)
  float* u     = combT + (size_t)D_ * B_;             // 4*D*B floats (25.2 MB)

  build_combT<<<dim3(B_ / 32, D_ / 32), 256, 0, stream>>>(x, hp, combT);
  kan_phase1<<<4 * D_, 256, 0, stream>>>(combT, W1, b1, W2, b2, u);
  kan_phase2<<<dim3(B_ / BT, H_ / HT), 256, 0, stream>>>(u, Wc, bc, cp, out);
}

// Round 2
// 95.368 us; speedup vs baseline: 2.3644x; 2.3644x over previous
//
#include <hip/hip_runtime.h>

#define B_  2048
#define I_  256
#define H_  512
#define D_  768
#define K_  32

typedef unsigned short ushort_t;
typedef unsigned int uint_t;
typedef __attribute__((ext_vector_type(8))) __bf16 bf16x8;
typedef __attribute__((ext_vector_type(4))) float f32x4;

__device__ __forceinline__ ushort_t f2bf(float f) {
  uint_t u = __float_as_uint(f);
  u += 0x7fffu + ((u >> 16) & 1u);   // RNE
  return (ushort_t)(u >> 16);
}
__device__ __forceinline__ float fast_sigmoid(float x) {
  return 1.f / (1.f + __expf(-x));
}
__device__ __forceinline__ float fast_tanh(float x) {
  float t = __expf(2.f * fabsf(x));          // overflow -> inf -> r = 1
  float r = 1.f - 2.f / (t + 1.f);
  return copysignf(r, x);
}

// ---- T0: W1,b1,W2 [g][d][k] -> [g][k][d] fp32 ----
__global__ __launch_bounds__(256) void transpose_w_small(
    const float* __restrict__ W1, const float* __restrict__ b1,
    const float* __restrict__ W2,
    float* __restrict__ w1t, float* __restrict__ b1t, float* __restrict__ w2t) {
  const float* src = (blockIdx.z == 0) ? W1 : (blockIdx.z == 1) ? b1 : W2;
  float* dst       = (blockIdx.z == 0) ? w1t : (blockIdx.z == 1) ? b1t : w2t;
  int g = blockIdx.y;
  int d0 = blockIdx.x * 32;
  __shared__ float t[32][33];
  int tx = threadIdx.x & 31, ty = threadIdx.x >> 5;
#pragma unroll
  for (int i = 0; i < 4; ++i) {
    int r = ty + i * 8;
    t[r][tx] = src[((size_t)g * D_ + d0 + r) * K_ + tx];
  }
  __syncthreads();
#pragma unroll
  for (int i = 0; i < 4; ++i) {
    int r = ty + i * 8;                       // k index
    dst[((size_t)g * K_ + r) * D_ + d0 + tx] = t[tx][r];
  }
}

// ---- T1: Wc [g][d][h] fp32 -> WcT [g][h][d] bf16 ----
__global__ __launch_bounds__(256) void transpose_wc(
    const float* __restrict__ Wc, ushort_t* __restrict__ wcT) {
  int g = blockIdx.z;
  int d0 = blockIdx.x * 32, h0 = blockIdx.y * 32;
  __shared__ float t[32][33];
  int tx = threadIdx.x & 31, ty = threadIdx.x >> 5;
#pragma unroll
  for (int i = 0; i < 4; ++i) {
    int r = ty + i * 8;
    t[r][tx] = Wc[((size_t)g * D_ + d0 + r) * H_ + h0 + tx];
  }
  __syncthreads();
#pragma unroll
  for (int i = 0; i < 4; ++i) {
    int r = ty + i * 8;                       // h index
    wcT[((size_t)g * H_ + h0 + r) * D_ + d0 + tx] = f2bf(t[tx][r]);
  }
}

// ---- phase 1: per-feature KAN MLP, weights in registers, writes uT[g][b][d] bf16 ----
__global__ __launch_bounds__(256) void kan_phase1(
    const float* __restrict__ x, const float* __restrict__ hp,
    const float* __restrict__ w1t, const float* __restrict__ b1t,
    const float* __restrict__ w2t, const float* __restrict__ b2,
    ushort_t* __restrict__ uT) {
  int bi = blockIdx.x;
  int g = bi & 3;
  int rest = bi >> 2;
  int dc = rest % 3;                 // 0: x[:,0:256], 1: hp[:,0:256], 2: hp[:,256:512]
  int bc = rest / 3;                 // 0..63, 32 batch rows each
  int t = threadIdx.x;
  int d = dc * 256 + t;

  float w1[K_], bb[K_], w2[K_];
#pragma unroll
  for (int k = 0; k < K_; ++k) {
    w1[k] = w1t[((size_t)g * K_ + k) * D_ + d];
    bb[k] = b1t[((size_t)g * K_ + k) * D_ + d];
    w2[k] = w2t[((size_t)g * K_ + k) * D_ + d];
  }
  float bias = b2[(size_t)g * D_ + d];

  const float* src = (dc == 0) ? (x + t) : (hp + ((dc == 1) ? t : t + 256));
  int stride = (dc == 0) ? I_ : H_;
  int b0 = bc * 32;

  for (int bb4 = 0; bb4 < 32; bb4 += 4) {
    float cv[4], acc[4];
#pragma unroll
    for (int j = 0; j < 4; ++j) {
      cv[j] = src[(size_t)(b0 + bb4 + j) * stride];
      acc[j] = bias;
    }
#pragma unroll
    for (int k = 0; k < K_; ++k) {
#pragma unroll
      for (int j = 0; j < 4; ++j) {
        float h = fmaxf(fmaf(cv[j], w1[k], bb[k]), 0.f);
        acc[j] = fmaf(h, w2[k], acc[j]);
      }
    }
#pragma unroll
    for (int j = 0; j < 4; ++j)
      uT[((size_t)g * B_ + b0 + bb4 + j) * D_ + d] = f2bf(acc[j]);
  }
}

// ---- phase 2: gates = uT @ Wc (bf16 MFMA) + fused LSTM epilogue ----
// block: 64(b) x 64(h) tile, all 4 gates, wave w computes gate w.
// LDS: A stage 2x[4][64][40] shorts (40960 B) + B stage 2x[4][64][40] (40960 B);
//      epilogue reuses it as float gate tiles [4][64][68] (69632 B). Total 81920 B.
__global__ __launch_bounds__(256) void kan_phase2(
    const ushort_t* __restrict__ uT, const ushort_t* __restrict__ wcT,
    const float* __restrict__ bc, const float* __restrict__ cprev,
    float* __restrict__ out) {
  __shared__ __align__(16) char smem[81920];
  int b0 = blockIdx.x * 64;
  int h0 = blockIdx.y * 64;
  int t = threadIdx.x;
  int w = t >> 6;                    // wave id = gate id
  int lane = t & 63;

  f32x4 acc[4][4];
#pragma unroll
  for (int m = 0; m < 4; ++m)
#pragma unroll
    for (int n = 0; n < 4; ++n) acc[m][n] = (f32x4){0.f, 0.f, 0.f, 0.f};

  uint4 ra[4], rb[4];
  auto gload = [&](int dk) {
#pragma unroll
    for (int i = 0; i < 4; ++i) {
      int c = t + i * 256;           // 0..1023
      int row = c >> 2;              // 0..255 = g*64 + r
      int cc = c & 3;                // 16B chunk within 64B row
      int gg = row >> 6, rr = row & 63;
      ra[i] = *(const uint4*)(uT + ((size_t)gg * B_ + b0 + rr) * D_ + dk + cc * 8);
      rb[i] = *(const uint4*)(wcT + ((size_t)gg * H_ + h0 + rr) * D_ + dk + cc * 8);
    }
  };
  auto lstore = [&](int bi) {
#pragma unroll
    for (int i = 0; i < 4; ++i) {
      int c = t + i * 256;
      int row = c >> 2;
      int cc = c & 3;
      *(uint4*)(smem + bi * 20480 + row * 80 + cc * 16) = ra[i];
      *(uint4*)(smem + 40960 + bi * 20480 + row * 80 + cc * 16) = rb[i];
    }
  };

  int frow = lane & 15;
  int fk = (lane >> 4) * 16;         // byte offset of this lane's 8-bf16 k-chunk

  gload(0);
  lstore(0);
  __syncthreads();
  for (int s = 0; s < 24; ++s) {
    int bi = s & 1;
    if (s + 1 < 24) gload((s + 1) * 32);   // prefetch next K-tile into regs
    bf16x8 af[4], bf[4];
#pragma unroll
    for (int m = 0; m < 4; ++m)
      af[m] = *(const bf16x8*)(smem + bi * 20480 + (w * 64 + m * 16 + frow) * 80 + fk);
#pragma unroll
    for (int n = 0; n < 4; ++n)
      bf[n] = *(const bf16x8*)(smem + 40960 + bi * 20480 + (w * 64 + n * 16 + frow) * 80 + fk);
#pragma unroll
    for (int m = 0; m < 4; ++m)
#pragma unroll
      for (int n = 0; n < 4; ++n)
        acc[m][n] = __builtin_amdgcn_mfma_f32_16x16x32_bf16(af[m], bf[n], acc[m][n], 0, 0, 0);
    if (s + 1 < 24) lstore(bi ^ 1);        // write next tile into other buffer
    __syncthreads();
  }

  // ---- epilogue: exchange gate tiles via LDS, then LSTM math ----
  float* gf = (float*)smem;                 // [4][64][68]
#pragma unroll
  for (int m = 0; m < 4; ++m)
#pragma unroll
    for (int n = 0; n < 4; ++n)
#pragma unroll
      for (int e = 0; e < 4; ++e) {
        int row = m * 16 + (lane >> 4) * 4 + e;
        int col = n * 16 + (lane & 15);
        gf[((size_t)w * 64 + row) * 68 + col] = acc[m][n][e];
      }
  __syncthreads();

  int row = w * 16 + (lane >> 2);           // wave w handles b-rows w*16..+16
  int cb = (lane & 3) * 4;
  int b = b0 + row;
#pragma unroll
  for (int jj = 0; jj < 4; ++jj) {
    int hc = h0 + cb + jj * 16;
    f32x4 g0 = *(const f32x4*)&gf[((size_t)0 * 64 + row) * 68 + cb + jj * 16];
    f32x4 g1 = *(const f32x4*)&gf[((size_t)1 * 64 + row) * 68 + cb + jj * 16];
    f32x4 g2 = *(const f32x4*)&gf[((size_t)2 * 64 + row) * 68 + cb + jj * 16];
    f32x4 g3 = *(const f32x4*)&gf[((size_t)3 * 64 + row) * 68 + cb + jj * 16];
    f32x4 cp = *(const f32x4*)&cprev[(size_t)b * H_ + hc];
    f32x4 hv, cv;
#pragma unroll
    for (int e = 0; e < 4; ++e) {
      float gF = g0[e] + bc[0 * H_ + hc + e];
      float gI = g1[e] + bc[1 * H_ + hc + e];
      float gO = g2[e] + bc[2 * H_ + hc + e];
      float gC = g3[e] + bc[3 * H_ + hc + e];
      float ft = fast_sigmoid(gF);
      float it = fast_sigmoid(gI);
      float ot = fast_sigmoid(gO);
      float tc = fast_tanh(gC);
      float cn = ft * cp[e] + it * tc;
      cv[e] = cn;
      hv[e] = ot * fast_tanh(cn);
    }
    *(f32x4*)&out[(size_t)b * H_ + hc] = hv;
    *(f32x4*)&out[(size_t)B_ * H_ + (size_t)b * H_ + hc] = cv;
  }
}

extern "C" void kernel_launch(void* const* d_in, const int* in_sizes, int n_in,
                              void* d_out, int out_size, void* d_ws, size_t ws_size,
                              hipStream_t stream) {
  const float* x  = (const float*)d_in[0];
  const float* hp = (const float*)d_in[1];
  const float* cp = (const float*)d_in[2];
  const float* W1 = (const float*)d_in[3];
  const float* b1 = (const float*)d_in[4];
  const float* W2 = (const float*)d_in[5];
  const float* b2 = (const float*)d_in[6];
  const float* Wc = (const float*)d_in[7];
  const float* bc = (const float*)d_in[8];
  float* out = (float*)d_out;

  // workspace layout
  float* w1t = (float*)d_ws;                        // 4*32*768 = 98304 f
  float* b1t = w1t + 98304;
  float* w2t = b1t + 98304;
  ushort_t* wcT = (ushort_t*)(w2t + 98304);         // 4*512*768 bf16
  ushort_t* uT  = wcT + (size_t)4 * H_ * D_;        // 4*2048*768 bf16

  transpose_w_small<<<dim3(24, 4, 3), 256, 0, stream>>>(W1, b1, W2, w1t, b1t, w2t);
  transpose_wc<<<dim3(24, 16, 4), 256, 0, stream>>>(Wc, wcT);
  kan_phase1<<<768, 256, 0, stream>>>(x, hp, w1t, b1t, w2t, b2, uT);
  kan_phase2<<<dim3(32, 8), 256, 0, stream>>>(uT, wcT, bc, cp, out);
}

// Round 3
// 56.071 us; speedup vs baseline: 4.0215x; 1.7008x over previous
//
#include <hip/hip_runtime.h>

#define B_  2048
#define I_  256
#define H_  512
#define D_  768
#define K_  32

typedef unsigned short ushort_t;
typedef unsigned int uint_t;
typedef __attribute__((ext_vector_type(8))) __bf16 bf16x8;
typedef __attribute__((ext_vector_type(4))) float f32x4;

__device__ __forceinline__ ushort_t f2bf(float f) {
  uint_t u = __float_as_uint(f);
  u += 0x7fffu + ((u >> 16) & 1u);   // RNE
  return (ushort_t)(u >> 16);
}
__device__ __forceinline__ float fast_sigmoid(float x) {
  return 1.f / (1.f + __expf(-x));
}
__device__ __forceinline__ float fast_tanh(float x) {
  float t = __expf(2.f * fabsf(x));          // overflow -> inf -> r = 1
  float r = 1.f - 2.f / (t + 1.f);
  return copysignf(r, x);
}
__device__ __forceinline__ void gload16(const void* g, void* l) {
  __builtin_amdgcn_global_load_lds(
      (const __attribute__((address_space(1))) void*)g,
      (__attribute__((address_space(3))) void*)l, 16, 0, 0);
}

// ---- T0: W1,b1,W2 [g][d][k] -> [g][k][d] fp32 ----
__global__ __launch_bounds__(256) void transpose_w_small(
    const float* __restrict__ W1, const float* __restrict__ b1,
    const float* __restrict__ W2,
    float* __restrict__ w1t, float* __restrict__ b1t, float* __restrict__ w2t) {
  const float* src = (blockIdx.z == 0) ? W1 : (blockIdx.z == 1) ? b1 : W2;
  float* dst       = (blockIdx.z == 0) ? w1t : (blockIdx.z == 1) ? b1t : w2t;
  int g = blockIdx.y;
  int d0 = blockIdx.x * 32;
  __shared__ float t[32][33];
  int tx = threadIdx.x & 31, ty = threadIdx.x >> 5;
#pragma unroll
  for (int i = 0; i < 4; ++i) {
    int r = ty + i * 8;
    t[r][tx] = src[((size_t)g * D_ + d0 + r) * K_ + tx];
  }
  __syncthreads();
#pragma unroll
  for (int i = 0; i < 4; ++i) {
    int r = ty + i * 8;                       // k index
    dst[((size_t)g * K_ + r) * D_ + d0 + tx] = t[tx][r];
  }
}

// ---- T1: Wc [g][d][h] fp32 -> WcT [g][h][d] bf16 ----
__global__ __launch_bounds__(256) void transpose_wc(
    const float* __restrict__ Wc, ushort_t* __restrict__ wcT) {
  int g = blockIdx.z;
  int d0 = blockIdx.x * 32, h0 = blockIdx.y * 32;
  __shared__ float t[32][33];
  int tx = threadIdx.x & 31, ty = threadIdx.x >> 5;
#pragma unroll
  for (int i = 0; i < 4; ++i) {
    int r = ty + i * 8;
    t[r][tx] = Wc[((size_t)g * D_ + d0 + r) * H_ + h0 + tx];
  }
  __syncthreads();
#pragma unroll
  for (int i = 0; i < 4; ++i) {
    int r = ty + i * 8;                       // h index
    wcT[((size_t)g * H_ + h0 + r) * D_ + d0 + tx] = f2bf(t[tx][r]);
  }
}

// ---- phase 1: per-feature KAN MLP, weights in registers, writes uT[g][b][d] bf16 ----
__global__ __launch_bounds__(256) void kan_phase1(
    const float* __restrict__ x, const float* __restrict__ hp,
    const float* __restrict__ w1t, const float* __restrict__ b1t,
    const float* __restrict__ w2t, const float* __restrict__ b2,
    ushort_t* __restrict__ uT) {
  int bi = blockIdx.x;
  int g = bi & 3;
  int rest = bi >> 2;
  int dc = rest % 3;                 // 0: x[:,0:256], 1: hp[:,0:256], 2: hp[:,256:512]
  int bc = rest / 3;                 // 0..63, 32 batch rows each
  int t = threadIdx.x;
  int d = dc * 256 + t;

  float w1[K_], bb[K_], w2[K_];
#pragma unroll
  for (int k = 0; k < K_; ++k) {
    w1[k] = w1t[((size_t)g * K_ + k) * D_ + d];
    bb[k] = b1t[((size_t)g * K_ + k) * D_ + d];
    w2[k] = w2t[((size_t)g * K_ + k) * D_ + d];
  }
  float bias = b2[(size_t)g * D_ + d];

  const float* src = (dc == 0) ? (x + t) : (hp + ((dc == 1) ? t : t + 256));
  int stride = (dc == 0) ? I_ : H_;
  int b0 = bc * 32;

  for (int bb4 = 0; bb4 < 32; bb4 += 4) {
    float cv[4], acc[4];
#pragma unroll
    for (int j = 0; j < 4; ++j) {
      cv[j] = src[(size_t)(b0 + bb4 + j) * stride];
      acc[j] = bias;
    }
#pragma unroll
    for (int k = 0; k < K_; ++k) {
#pragma unroll
      for (int j = 0; j < 4; ++j) {
        float h = fmaxf(fmaf(cv[j], w1[k], bb[k]), 0.f);
        acc[j] = fmaf(h, w2[k], acc[j]);
      }
    }
#pragma unroll
    for (int j = 0; j < 4; ++j)
      uT[((size_t)g * B_ + b0 + bb4 + j) * D_ + d] = f2bf(acc[j]);
  }
}

// ---- phase 2 v3: 32(b) x 64(h) x 4 gates per block, 8 waves, global_load_lds,
//      XOR-swizzled LDS, single-barrier double-buffered K loop, fused LSTM ----
#define TB 32
#define TH 64
#define BK 32
#define NT (D_ / BK)                 // 24
#define BUFSZ 24576                  // A 8KB + B 16KB per buffer

__global__ __launch_bounds__(512, 4) void kan_phase2(
    const ushort_t* __restrict__ uT, const ushort_t* __restrict__ wcT,
    const float* __restrict__ bc, const float* __restrict__ cprev,
    float* __restrict__ out) {
  __shared__ __align__(16) char smem[49152];
  const int b0 = blockIdx.x * TB;
  const int h0 = blockIdx.y * TH;
  const int t = threadIdx.x;
  const int w = t >> 6;
  const int l = t & 63;

  // ---- staging source addresses (pre-swizzled global chunks, linear LDS dest) ----
  // A: wave w stages A-part w: gate w>>1, rows (w&1)*16..+16
  const int ag   = w >> 1;
  const int arow = (w & 1) * 16 + (l >> 2);
  const int acg  = (l & 3) ^ ((arow ^ (arow >> 2)) & 3);
  const ushort_t* asrc = uT + ((size_t)ag * B_ + b0 + arow) * D_ + acg * 8;
  // B: wave w stages B-parts w and w+8: part j -> gate j>>2, rows (j&3)*16..+16
  const int bg0  = w >> 2;
  const int brow = (w & 3) * 16 + (l >> 2);
  const int bcg  = (l & 3) ^ ((brow ^ (brow >> 2)) & 3);
  const ushort_t* bsrc0 = wcT + ((size_t)bg0 * H_ + h0 + brow) * D_ + bcg * 8;
  const ushort_t* bsrc1 = bsrc0 + (size_t)2 * H_ * D_;
  char* aldst  = smem + (w << 10) + (l << 4);
  char* bldst0 = smem + 8192 + (w << 10) + (l << 4);
  char* bldst1 = smem + 8192 + ((w + 8) << 10) + (l << 4);

  // ---- compute-side LDS byte offsets (read swizzle matches source permutation) ----
  const int gate = w >> 1, nh = w & 1;
  const int frow = l & 15, c0 = l >> 4;
  const int cx = ((c0 ^ ((frow ^ (frow >> 2)) & 3)) << 4);
  int aoff[2], boff[2];
#pragma unroll
  for (int m = 0; m < 2; ++m)
    aoff[m] = ((gate * 32 + m * 16 + frow) << 6) + cx;
#pragma unroll
  for (int n = 0; n < 2; ++n)
    boff[n] = 8192 + ((gate * 64 + nh * 32 + n * 16 + frow) << 6) + cx;

  // ---- accumulators, bias folded in (C col = lane&15) ----
  f32x4 acc[2][2];
#pragma unroll
  for (int n = 0; n < 2; ++n) {
    float bv = bc[(size_t)gate * H_ + h0 + nh * 32 + n * 16 + frow];
#pragma unroll
    for (int m = 0; m < 2; ++m) acc[m][n] = (f32x4){bv, bv, bv, bv};
  }

  auto stage = [&](int buf, int dke) {
    gload16(asrc + dke, aldst + buf * BUFSZ);
    gload16(bsrc0 + dke, bldst0 + buf * BUFSZ);
    gload16(bsrc1 + dke, bldst1 + buf * BUFSZ);
  };

  stage(0, 0);
  for (int s = 0; s < NT; ++s) {
    __syncthreads();                       // drains stage(s); prior buf reads done
    const char* bb = smem + (s & 1) * BUFSZ;
    if (s + 1 < NT) stage((s + 1) & 1, (s + 1) * BK);
    bf16x8 af0 = *(const bf16x8*)(bb + aoff[0]);
    bf16x8 af1 = *(const bf16x8*)(bb + aoff[1]);
    bf16x8 bf0 = *(const bf16x8*)(bb + boff[0]);
    bf16x8 bf1 = *(const bf16x8*)(bb + boff[1]);
    acc[0][0] = __builtin_amdgcn_mfma_f32_16x16x32_bf16(af0, bf0, acc[0][0], 0, 0, 0);
    acc[0][1] = __builtin_amdgcn_mfma_f32_16x16x32_bf16(af0, bf1, acc[0][1], 0, 0, 0);
    acc[1][0] = __builtin_amdgcn_mfma_f32_16x16x32_bf16(af1, bf0, acc[1][0], 0, 0, 0);
    acc[1][1] = __builtin_amdgcn_mfma_f32_16x16x32_bf16(af1, bf1, acc[1][1], 0, 0, 0);
  }
  __syncthreads();                         // all reads done before gf overlay

  // ---- epilogue: exchange gate tiles via LDS [4][32][68] f32, fused LSTM ----
  float* gf = (float*)smem;
#pragma unroll
  for (int m = 0; m < 2; ++m)
#pragma unroll
    for (int n = 0; n < 2; ++n)
#pragma unroll
      for (int e = 0; e < 4; ++e) {
        int row = m * 16 + (l >> 4) * 4 + e;
        int col = nh * 32 + n * 16 + frow;
        gf[((size_t)gate * 32 + row) * 68 + col] = acc[m][n][e];
      }
  __syncthreads();

  {
    int row = t >> 4;                      // 0..31
    int ch = t & 15;                       // h-chunk of 4
    int b = b0 + row;
    int hc = h0 + ch * 4;
    f32x4 g0 = *(const f32x4*)&gf[((size_t)0 * 32 + row) * 68 + ch * 4];
    f32x4 g1 = *(const f32x4*)&gf[((size_t)1 * 32 + row) * 68 + ch * 4];
    f32x4 g2 = *(const f32x4*)&gf[((size_t)2 * 32 + row) * 68 + ch * 4];
    f32x4 g3 = *(const f32x4*)&gf[((size_t)3 * 32 + row) * 68 + ch * 4];
    f32x4 cp = *(const f32x4*)&cprev[(size_t)b * H_ + hc];
    f32x4 hv, cv;
#pragma unroll
    for (int e = 0; e < 4; ++e) {
      float ft = fast_sigmoid(g0[e]);
      float it = fast_sigmoid(g1[e]);
      float ot = fast_sigmoid(g2[e]);
      float tc = fast_tanh(g3[e]);
      float cn = ft * cp[e] + it * tc;
      cv[e] = cn;
      hv[e] = ot * fast_tanh(cn);
    }
    *(f32x4*)&out[(size_t)b * H_ + hc] = hv;
    *(f32x4*)&out[(size_t)B_ * H_ + (size_t)b * H_ + hc] = cv;
  }
}

extern "C" void kernel_launch(void* const* d_in, const int* in_sizes, int n_in,
                              void* d_out, int out_size, void* d_ws, size_t ws_size,
                              hipStream_t stream) {
  const float* x  = (const float*)d_in[0];
  const float* hp = (const float*)d_in[1];
  const float* cp = (const float*)d_in[2];
  const float* W1 = (const float*)d_in[3];
  const float* b1 = (const float*)d_in[4];
  const float* W2 = (const float*)d_in[5];
  const float* b2 = (const float*)d_in[6];
  const float* Wc = (const float*)d_in[7];
  const float* bc = (const float*)d_in[8];
  float* out = (float*)d_out;

  // workspace layout
  float* w1t = (float*)d_ws;                        // 4*32*768 = 98304 f
  float* b1t = w1t + 98304;
  float* w2t = b1t + 98304;
  ushort_t* wcT = (ushort_t*)(w2t + 98304);         // 4*512*768 bf16
  ushort_t* uT  = wcT + (size_t)4 * H_ * D_;        // 4*2048*768 bf16

  transpose_w_small<<<dim3(24, 4, 3), 256, 0, stream>>>(W1, b1, W2, w1t, b1t, w2t);
  transpose_wc<<<dim3(24, 16, 4), 256, 0, stream>>>(Wc, wcT);
  kan_phase1<<<768, 256, 0, stream>>>(x, hp, w1t, b1t, w2t, b2, uT);
  kan_phase2<<<dim3(B_ / TB, H_ / TH), 512, 0, stream>>>(uT, wcT, bc, cp, out);
}

// Round 4
// 50.799 us; speedup vs baseline: 4.4389x; 1.1038x over previous
//
#include <hip/hip_runtime.h>

#define B_  2048
#define I_  256
#define H_  512
#define D_  768
#define K_  32

typedef unsigned short ushort_t;
typedef unsigned int uint_t;
typedef __attribute__((ext_vector_type(8))) __bf16 bf16x8;
typedef __attribute__((ext_vector_type(4))) float f32x4;

__device__ __forceinline__ ushort_t f2bf(float f) {
  uint_t u = __float_as_uint(f);
  u += 0x7fffu + ((u >> 16) & 1u);   // RNE
  return (ushort_t)(u >> 16);
}
__device__ __forceinline__ float fast_sigmoid(float x) {
  return 1.f / (1.f + __expf(-x));
}
__device__ __forceinline__ float fast_tanh(float x) {
  float t = __expf(2.f * fabsf(x));          // overflow -> inf -> r = 1
  float r = 1.f - 2.f / (t + 1.f);
  return copysignf(r, x);
}
__device__ __forceinline__ void gload16(const void* g, void* l) {
  __builtin_amdgcn_global_load_lds(
      (const __attribute__((address_space(1))) void*)g,
      (__attribute__((address_space(3))) void*)l, 16, 0, 0);
}

// ---- merged transposes:
//  blocks 0..287:    W1,b1,W2 [g][d][k] -> [g][k][d] fp32
//  blocks 288..1823: Wc [g][d][h] fp32 -> WcT [g][h][d] bf16
__global__ __launch_bounds__(256) void transpose_all(
    const float* __restrict__ W1, const float* __restrict__ b1,
    const float* __restrict__ W2, const float* __restrict__ Wc,
    float* __restrict__ w1t, float* __restrict__ b1t, float* __restrict__ w2t,
    ushort_t* __restrict__ wcT) {
  __shared__ float t[32][33];
  int tx = threadIdx.x & 31, ty = threadIdx.x >> 5;
  int bid = blockIdx.x;
  if (bid < 288) {
    int z = bid / 96;                 // 0:W1 1:b1 2:W2
    int g = (bid / 24) % 4;
    int d0 = (bid % 24) * 32;
    const float* src = (z == 0) ? W1 : (z == 1) ? b1 : W2;
    float* dst       = (z == 0) ? w1t : (z == 1) ? b1t : w2t;
#pragma unroll
    for (int i = 0; i < 4; ++i) {
      int r = ty + i * 8;
      t[r][tx] = src[((size_t)g * D_ + d0 + r) * K_ + tx];
    }
    __syncthreads();
#pragma unroll
    for (int i = 0; i < 4; ++i) {
      int r = ty + i * 8;                     // k index
      dst[((size_t)g * K_ + r) * D_ + d0 + tx] = t[tx][r];
    }
  } else {
    int r2 = bid - 288;
    int g = r2 / 384;
    int rem = r2 % 384;
    int d0 = (rem / 16) * 32;
    int h0 = (rem % 16) * 32;
#pragma unroll
    for (int i = 0; i < 4; ++i) {
      int r = ty + i * 8;
      t[r][tx] = Wc[((size_t)g * D_ + d0 + r) * H_ + h0 + tx];
    }
    __syncthreads();
#pragma unroll
    for (int i = 0; i < 4; ++i) {
      int r = ty + i * 8;                     // h index
      wcT[((size_t)g * H_ + h0 + r) * D_ + d0 + tx] = f2bf(t[tx][r]);
    }
  }
}

// ---- phase 1: per-feature KAN MLP, weights in registers, writes uT[g][b][d] bf16 ----
__global__ __launch_bounds__(256) void kan_phase1(
    const float* __restrict__ x, const float* __restrict__ hp,
    const float* __restrict__ w1t, const float* __restrict__ b1t,
    const float* __restrict__ w2t, const float* __restrict__ b2,
    ushort_t* __restrict__ uT) {
  int bi = blockIdx.x;
  int g = bi & 3;
  int rest = bi >> 2;
  int dc = rest % 3;                 // 0: x[:,0:256], 1: hp[:,0:256], 2: hp[:,256:512]
  int bc = rest / 3;                 // 0..63, 32 batch rows each
  int t = threadIdx.x;
  int d = dc * 256 + t;

  float w1[K_], bb[K_], w2[K_];
#pragma unroll
  for (int k = 0; k < K_; ++k) {
    w1[k] = w1t[((size_t)g * K_ + k) * D_ + d];
    bb[k] = b1t[((size_t)g * K_ + k) * D_ + d];
    w2[k] = w2t[((size_t)g * K_ + k) * D_ + d];
  }
  float bias = b2[(size_t)g * D_ + d];

  const float* src = (dc == 0) ? (x + t) : (hp + ((dc == 1) ? t : t + 256));
  int stride = (dc == 0) ? I_ : H_;
  int b0 = bc * 32;

#pragma unroll
  for (int bb8 = 0; bb8 < 32; bb8 += 8) {
    float cv[8], acc[8];
#pragma unroll
    for (int j = 0; j < 8; ++j) {
      cv[j] = src[(size_t)(b0 + bb8 + j) * stride];
      acc[j] = bias;
    }
#pragma unroll
    for (int k = 0; k < K_; ++k) {
#pragma unroll
      for (int j = 0; j < 8; ++j) {
        float h = fmaxf(fmaf(cv[j], w1[k], bb[k]), 0.f);
        acc[j] = fmaf(h, w2[k], acc[j]);
      }
    }
#pragma unroll
    for (int j = 0; j < 8; ++j)
      uT[((size_t)g * B_ + b0 + bb8 + j) * D_ + d] = f2bf(acc[j]);
  }
}

// ---- phase 2 v4: 32(b) x 64(h) x 4 gates per block, 8 waves,
//      global_load_lds + 3-deep buffer pipeline with counted vmcnt (T3+T4),
//      XOR-swizzled LDS reads, fused LSTM epilogue ----
#define TB 32
#define TH 64
#define BK 32
#define NT (D_ / BK)                 // 24
#define BUFSZ 24576                  // A 8KB + B 16KB per buffer
#define NBUF 3

__global__ __launch_bounds__(512, 4) void kan_phase2(
    const ushort_t* __restrict__ uT, const ushort_t* __restrict__ wcT,
    const float* __restrict__ bc, const float* __restrict__ cprev,
    float* __restrict__ out) {
  __shared__ __align__(16) char smem[NBUF * BUFSZ];   // 73728 B
  const int b0 = blockIdx.x * TB;
  const int h0 = blockIdx.y * TH;
  const int t = threadIdx.x;
  const int w = t >> 6;
  const int l = t & 63;

  // ---- staging source addresses (pre-swizzled global chunks, linear LDS dest) ----
  const int ag   = w >> 1;
  const int arow = (w & 1) * 16 + (l >> 2);
  const int acg  = (l & 3) ^ ((arow ^ (arow >> 2)) & 3);
  const ushort_t* asrc = uT + ((size_t)ag * B_ + b0 + arow) * D_ + acg * 8;
  const int bg0  = w >> 2;
  const int brow = (w & 3) * 16 + (l >> 2);
  const int bcg  = (l & 3) ^ ((brow ^ (brow >> 2)) & 3);
  const ushort_t* bsrc0 = wcT + ((size_t)bg0 * H_ + h0 + brow) * D_ + bcg * 8;
  const ushort_t* bsrc1 = bsrc0 + (size_t)2 * H_ * D_;
  const int aoffL  = (w << 10) + (l << 4);            // LDS offsets within a buffer
  const int boff0L = 8192 + (w << 10) + (l << 4);
  const int boff1L = 8192 + ((w + 8) << 10) + (l << 4);

  // ---- compute-side LDS byte offsets (read swizzle = same involution) ----
  const int gate = w >> 1, nh = w & 1;
  const int frow = l & 15, c0 = l >> 4;
  const int cx = ((c0 ^ ((frow ^ (frow >> 2)) & 3)) << 4);
  int aoff[2], boff[2];
#pragma unroll
  for (int m = 0; m < 2; ++m)
    aoff[m] = ((gate * 32 + m * 16 + frow) << 6) + cx;
#pragma unroll
  for (int n = 0; n < 2; ++n)
    boff[n] = 8192 + ((gate * 64 + nh * 32 + n * 16 + frow) << 6) + cx;

  // ---- accumulators, bias folded in (C col = lane&15) ----
  f32x4 acc[2][2];
#pragma unroll
  for (int n = 0; n < 2; ++n) {
    float bv = bc[(size_t)gate * H_ + h0 + nh * 32 + n * 16 + frow];
#pragma unroll
    for (int m = 0; m < 2; ++m) acc[m][n] = (f32x4){bv, bv, bv, bv};
  }

  auto stage = [&](int bufoff, int dke) {
    gload16(asrc + dke, smem + bufoff + aoffL);
    gload16(bsrc0 + dke, smem + bufoff + boff0L);
    gload16(bsrc1 + dke, smem + bufoff + boff1L);
  };
  auto compute = [&](const char* bb) {
    bf16x8 af0 = *(const bf16x8*)(bb + aoff[0]);
    bf16x8 af1 = *(const bf16x8*)(bb + aoff[1]);
    bf16x8 bf0 = *(const bf16x8*)(bb + boff[0]);
    bf16x8 bf1 = *(const bf16x8*)(bb + boff[1]);
    acc[0][0] = __builtin_amdgcn_mfma_f32_16x16x32_bf16(af0, bf0, acc[0][0], 0, 0, 0);
    acc[0][1] = __builtin_amdgcn_mfma_f32_16x16x32_bf16(af0, bf1, acc[0][1], 0, 0, 0);
    acc[1][0] = __builtin_amdgcn_mfma_f32_16x16x32_bf16(af1, bf0, acc[1][0], 0, 0, 0);
    acc[1][1] = __builtin_amdgcn_mfma_f32_16x16x32_bf16(af1, bf1, acc[1][1], 0, 0, 0);
  };

  // ---- prologue: 2 tiles in flight ----
  stage(0, 0);
  stage(BUFSZ, BK);
  int roff = 0, soff = 2 * BUFSZ;
  for (int s = 0; s < NT - 1; ++s) {
    // wait own stage(s) complete (3 newest = stage(s+1) stay in flight), then sync
    asm volatile("s_waitcnt vmcnt(3)" ::: "memory");
    __builtin_amdgcn_s_barrier();
    if (s + 2 < NT) {
      stage(soff, (s + 2) * BK);
      soff += BUFSZ; if (soff == NBUF * BUFSZ) soff = 0;
    }
    compute(smem + roff);
    roff += BUFSZ; if (roff == NBUF * BUFSZ) roff = 0;
  }
  asm volatile("s_waitcnt vmcnt(0)" ::: "memory");
  __builtin_amdgcn_s_barrier();
  compute(smem + roff);
  __syncthreads();                         // all LDS reads done before gf overlay

  // ---- epilogue: exchange gate tiles via LDS [4][32][68] f32, fused LSTM ----
  float* gf = (float*)smem;
#pragma unroll
  for (int m = 0; m < 2; ++m)
#pragma unroll
    for (int n = 0; n < 2; ++n)
#pragma unroll
      for (int e = 0; e < 4; ++e) {
        int row = m * 16 + (l >> 4) * 4 + e;
        int col = nh * 32 + n * 16 + frow;
        gf[((size_t)gate * 32 + row) * 68 + col] = acc[m][n][e];
      }
  __syncthreads();

  {
    int row = t >> 4;                      // 0..31
    int ch = t & 15;                       // h-chunk of 4
    int b = b0 + row;
    int hc = h0 + ch * 4;
    f32x4 g0 = *(const f32x4*)&gf[((size_t)0 * 32 + row) * 68 + ch * 4];
    f32x4 g1 = *(const f32x4*)&gf[((size_t)1 * 32 + row) * 68 + ch * 4];
    f32x4 g2 = *(const f32x4*)&gf[((size_t)2 * 32 + row) * 68 + ch * 4];
    f32x4 g3 = *(const f32x4*)&gf[((size_t)3 * 32 + row) * 68 + ch * 4];
    f32x4 cp = *(const f32x4*)&cprev[(size_t)b * H_ + hc];
    f32x4 hv, cv;
#pragma unroll
    for (int e = 0; e < 4; ++e) {
      float ft = fast_sigmoid(g0[e]);
      float it = fast_sigmoid(g1[e]);
      float ot = fast_sigmoid(g2[e]);
      float tc = fast_tanh(g3[e]);
      float cn = ft * cp[e] + it * tc;
      cv[e] = cn;
      hv[e] = ot * fast_tanh(cn);
    }
    *(f32x4*)&out[(size_t)b * H_ + hc] = hv;
    *(f32x4*)&out[(size_t)B_ * H_ + (size_t)b * H_ + hc] = cv;
  }
}

extern "C" void kernel_launch(void* const* d_in, const int* in_sizes, int n_in,
                              void* d_out, int out_size, void* d_ws, size_t ws_size,
                              hipStream_t stream) {
  const float* x  = (const float*)d_in[0];
  const float* hp = (const float*)d_in[1];
  const float* cp = (const float*)d_in[2];
  const float* W1 = (const float*)d_in[3];
  const float* b1 = (const float*)d_in[4];
  const float* W2 = (const float*)d_in[5];
  const float* b2 = (const float*)d_in[6];
  const float* Wc = (const float*)d_in[7];
  const float* bc = (const float*)d_in[8];
  float* out = (float*)d_out;

  // workspace layout
  float* w1t = (float*)d_ws;                        // 4*32*768 = 98304 f
  float* b1t = w1t + 98304;
  float* w2t = b1t + 98304;
  ushort_t* wcT = (ushort_t*)(w2t + 98304);         // 4*512*768 bf16
  ushort_t* uT  = wcT + (size_t)4 * H_ * D_;        // 4*2048*768 bf16

  transpose_all<<<1824, 256, 0, stream>>>(W1, b1, W2, Wc, w1t, b1t, w2t, wcT);
  kan_phase1<<<768, 256, 0, stream>>>(x, hp, w1t, b1t, w2t, b2, uT);
  kan_phase2<<<dim3(B_ / TB, H_ / TH), 512, 0, stream>>>(uT, wcT, bc, cp, out);
}